// Round 13
// baseline (852.486 us; speedup 1.0000x reference)
//
#include <hip/hip_runtime.h>
#include <hip/hip_bf16.h>

typedef __attribute__((ext_vector_type(8))) short short8;
typedef __attribute__((ext_vector_type(4))) float floatx4;
typedef __attribute__((ext_vector_type(2))) unsigned short ushortx2;

#define NHID 128
#define PADROW 136   // u16 row stride: 272B, 16B-aligned b128, benign banking
#define EB 64        // nodes per tile (encdec / fallback)
#define EB2 128      // edges per tile (edge_sorted)
#define PB 256       // partitions for the fused sort (MUST equal its grid size)

__device__ __forceinline__ unsigned short f2bf(float x) {
  unsigned int u = __float_as_uint(x);
  u += 0x7FFFu + ((u >> 16) & 1u);          // RNE
  return (unsigned short)(u >> 16);
}

__device__ __forceinline__ unsigned int pkbf(float a, float b) {
  __hip_bfloat162 h = __float22bfloat162_rn(make_float2(a, b));
  union { __hip_bfloat162 h; unsigned int u; } cv;
  cv.h = h;
  return cv.u;
}

__device__ __forceinline__ unsigned int pack2(float a, float b) {
  return (unsigned int)f2bf(a) | ((unsigned int)f2bf(b) << 16);
}

// packed u16 max (v_pk_max_u16)
__device__ __forceinline__ unsigned int pkmax(unsigned int a, unsigned int b) {
  union { unsigned int u; ushortx2 v; } x, y;
  x.u = a; y.u = b;
  x.v = __builtin_elementwise_max(x.v, y.v);
  return x.u;
}

__device__ __forceinline__ void casmax(unsigned int* ap, unsigned int run) {
  unsigned int old = *ap;
  while (true) {
    unsigned int mx = pkmax(old, run);
    if (mx == old) break;
    unsigned int got = atomicCAS(ap, old, mx);
    if (got == old) break;
    old = got;
  }
}

// all-wave inline int64 probe: odd int32 slots all-zero <=> int64 edge_index
__device__ __forceinline__ bool detect64(const int* __restrict__ ei) {
  unsigned long long b = __ballot(ei[2 * (threadIdx.x & 63) + 1] != 0);
  return b == 0ULL;
}

// software grid barrier: monotonic device counter. All blocks co-resident
// (256 blocks x 1024 thr = 1 block/CU). cnt memset to 0 per launch.
__device__ __forceinline__ void gbar(unsigned int* cnt, unsigned int target) {
  __threadfence();     // release: my writes visible device-wide (cross-XCD)
  __syncthreads();     // all block threads done + fenced
  if (threadIdx.x == 0) {
    atomicAdd(cnt, 1u);
    while (atomicAdd(cnt, 0u) < target) __builtin_amdgcn_s_sleep(2);
  }
  __syncthreads();
  __threadfence();     // acquire: no stale reads after barrier
}

// 32 loop-invariant B-fragments of a 128x128 row-major f32 weight (registers), natural k.
__device__ __forceinline__ void load_bfrags(const float* __restrict__ wmat,
                                            short8* bf, int m, int q) {
  #pragma unroll
  for (int kc = 0; kc < 4; ++kc) {
    #pragma unroll
    for (int nt = 0; nt < 8; ++nt) {
      short8 v;
      #pragma unroll
      for (int j = 0; j < 8; ++j)
        v[j] = (short)f2bf(wmat[(kc * 32 + q * 8 + j) * NHID + nt * 16 + m]);
      bf[kc * 8 + nt] = v;
    }
  }
}

// same but k-permuted: B[khw][n] = w[pi(khw)][n], pi(k) = ((k&7)<<4)|(k>>3)
__device__ __forceinline__ void load_bfrags_perm(const float* __restrict__ wmat,
                                                 short8* bf, int m, int q) {
  #pragma unroll
  for (int kc = 0; kc < 4; ++kc) {
    #pragma unroll
    for (int nt = 0; nt < 8; ++nt) {
      short8 v;
      #pragma unroll
      for (int j = 0; j < 8; ++j) {
        const int khw = kc * 32 + q * 8 + j;
        const int ctrue = ((khw & 7) << 4) | (khw >> 3);
        v[j] = (short)f2bf(wmat[ctrue * NHID + nt * 16 + m]);
      }
      bf[kc * 8 + nt] = v;
    }
  }
}

__device__ __forceinline__ void mfma_block(const unsigned short* uA,
                                           const short8* bf, floatx4* acc,
                                           int w, int m, int q) {
  #pragma unroll
  for (int kc = 0; kc < 4; ++kc) {
    short8 a = *(const short8*)(uA + (16 * w + m) * PADROW + kc * 32 + q * 8);
    #pragma unroll
    for (int nt = 0; nt < 8; ++nt)
      acc[nt] = __builtin_amdgcn_mfma_f32_16x16x32_bf16(a, bf[kc * 8 + nt],
                                                        acc[nt], 0, 0, 0);
  }
}

// fallback-path zero (agg16) + detect->flag
__global__ void zero_detect_kernel(float4* __restrict__ p, int n4,
                                   const int* __restrict__ ei, int* __restrict__ flag) {
  if (blockIdx.x == 0 && threadIdx.x < 64) {
    unsigned long long b = __ballot(ei[2 * threadIdx.x + 1] != 0);
    if (threadIdx.x == 0) flag[0] = (b == 0ULL) ? 1 : 0;
  }
  int i = blockIdx.x * blockDim.x + threadIdx.x;
  int stride = gridDim.x * blockDim.x;
  float4 z = make_float4(0.f, 0.f, 0.f, 0.f);
  for (; i < n4; i += stride) p[i] = z;
}

// ---------------- fused 2-level counting sort by dst (single launch) ----------------
// 256 blocks x 1024 threads (16 waves/CU — R12's 256-thr version ran at 4 waves/CU
// and was latency-starved: 230 µs, occupancy 11.6%). Scans use threads t<256.
// phase 1: per-partition LDS histogram (dst>>8) + zero agg16
// phase 2: per-bucket exclusive scan over partitions + bucket totals
// phase 3: scatter into coarse-bucket regions (bucket starts scanned in-LDS)
// phase 4: per-bucket exact-dst counting sort

__global__ __launch_bounds__(1024) void sort_fused(
    const int* __restrict__ ei, int E, int nbuck,
    int* __restrict__ mat, int* __restrict__ btot, int* __restrict__ bstart,
    int2* __restrict__ mid, int2* __restrict__ sorted,
    float4* __restrict__ aggz, int n4, unsigned int* __restrict__ cnt) {
  __shared__ int shA[512];
  __shared__ int shB[512];
  const int bl = blockIdx.x, t = threadIdx.x;
  const bool is64 = detect64(ei);
  const int chunk = (E + PB - 1) / PB;
  const int lo = bl * chunk;
  const int hi = min(lo + chunk, E);

  // ---- phase 1 ----
  for (int i = t; i < nbuck; i += 1024) shA[i] = 0;
  __syncthreads();
  for (int i = lo + t; i < hi; i += 1024) {
    int d = is64 ? ei[2 * E + 2 * i] : ei[E + i];
    atomicAdd(&shA[d >> 8], 1);
  }
  {
    float4 z = make_float4(0.f, 0.f, 0.f, 0.f);
    for (int i = bl * 1024 + t; i < n4; i += PB * 1024) aggz[i] = z;
  }
  __syncthreads();
  for (int bu = t; bu < nbuck; bu += 1024) mat[bu * PB + bl] = shA[bu];
  gbar(cnt, PB * 1);

  // ---- phase 2 ----
  for (int bu = bl; bu < nbuck; bu += PB) {
    const int v = (t < 256) ? mat[bu * PB + t] : 0;
    if (t < 256) shA[t] = v;
    __syncthreads();
    for (int off = 1; off < 256; off <<= 1) {
      int x = (t >= off && t < 256) ? shA[t - off] : 0;
      __syncthreads();
      if (t < 256) shA[t] += x;
      __syncthreads();
    }
    if (t < 256) mat[bu * PB + t] = shA[t] - v;
    if (t == 255) btot[bu] = shA[255];
    __syncthreads();
  }
  gbar(cnt, PB * 2);

  // ---- phase 3 ----
  {
    const int o0 = (t < 256 && t < nbuck) ? btot[t] : 0;
    const int o1 = (t < 256 && t + 256 < nbuck) ? btot[t + 256] : 0;
    if (t < 256) { shA[t] = o0; shA[t + 256] = o1; }
    __syncthreads();
    for (int o = 1; o < 256; o <<= 1) {
      int x0 = (t >= o && t < 256) ? shA[t - o] : 0;
      int x1 = (t >= o && t < 256) ? shA[256 + t - o] : 0;
      __syncthreads();
      if (t < 256) { shA[t] += x0; shA[256 + t] += x1; }
      __syncthreads();
    }
    const int tot0 = shA[255];
    if (t < 256) shA[256 + t] += tot0;
    __syncthreads();
    if (t < 256) {
      const int ex0 = shA[t] - o0;
      const int ex1 = shA[256 + t] - o1;
      if (bl == 0) { bstart[t] = ex0; bstart[256 + t] = ex1; }
      shB[t]       = ex0 + ((t < nbuck) ? mat[t * PB + bl] : 0);
      shB[256 + t] = ex1 + ((t + 256 < nbuck) ? mat[(t + 256) * PB + bl] : 0);
    }
    __syncthreads();
    for (int i = lo + t; i < hi; i += 1024) {
      int s = is64 ? ei[2 * i]         : ei[i];
      int d = is64 ? ei[2 * E + 2 * i] : ei[E + i];
      int p = atomicAdd(&shB[d >> 8], 1);
      mid[p] = make_int2(s, d);
    }
  }
  gbar(cnt, PB * 3);

  // ---- phase 4 ----
  for (int bu = bl; bu < nbuck; bu += PB) {
    const int blo = bstart[bu], bhi = bstart[bu + 1];
    if (t < 256) { shA[t] = 0; shB[t] = 0; }
    __syncthreads();
    for (int i = blo + t; i < bhi; i += 1024) atomicAdd(&shA[mid[i].y & 255], 1);
    __syncthreads();
    const int v = (t < 256) ? shA[t] : 0;
    for (int off = 1; off < 256; off <<= 1) {
      int x = (t >= off && t < 256) ? shA[t - off] : 0;
      __syncthreads();
      if (t < 256) shA[t] += x;
      __syncthreads();
    }
    int excl = 0;
    if (t < 256) excl = shA[t] - v;
    __syncthreads();
    if (t < 256) shA[t] = excl;
    __syncthreads();
    for (int i = blo + t; i < bhi; i += 1024) {
      int2 e = mid[i];
      const int dl = e.y & 255;
      const int p = blo + shA[dl] + atomicAdd(&shB[dl], 1);
      sorted[p] = e;
    }
    __syncthreads();
  }
}

// ---------------- fused edge MLP (both layers MFMA) + segmented max ----------------
// R9 structure (barriers A/B/C/D/E/F): barrier lockstep is a beneficial scheduling
// fence — R10's barrier removal raised VGPR 60->92 and regressed 178->260 µs.
// agg16: u16[N][128] in kstore (k-permuted) order. Stage-3: two-pass LDS run merge.

__global__ __launch_bounds__(512, 2) void edge_sorted_kernel(
    const float* __restrict__ x, const int2* __restrict__ sorted,
    const float* __restrict__ w1, const float* __restrict__ b1,
    const float* __restrict__ w2, const float* __restrict__ b2,
    unsigned int* aggu, int N, int E) {
  __shared__ unsigned short us[EB2 * PADROW];     // uA then hS (bf16)
  __shared__ short8 w2f[2048];                    // 32 frags x 64 lanes, k-permuted
  __shared__ int esS[EB2], edS[EB2];
  __shared__ int pn[2];                           // dst before / after tile (-2 = none)
  __shared__ unsigned long long maskS[2];         // run-start bitmask
  __shared__ unsigned int pmS[8][64];             // per-quarter partial of run covering r0

  const int t = threadIdx.x;
  const int lane = t & 63;
  const int w = t >> 6;                           // wave 0..7
  const int m = lane & 15;
  const int q = lane >> 4;

  float b1c[8], b2c[8];
  #pragma unroll
  for (int nt = 0; nt < 8; ++nt) { b1c[nt] = b1[nt * 16 + m]; b2c[nt] = b2[nt * 16 + m]; }

  short8 bf1[8];
  #pragma unroll
  for (int nt = 0; nt < 8; ++nt) {
    short8 v;
    #pragma unroll
    for (int j = 0; j < 8; ++j)
      v[j] = (q == 0 && j < 6) ? (short)f2bf(w1[j * NHID + nt * 16 + m]) : (short)0;
    bf1[nt] = v;
  }

  for (int idx = t; idx < 2048; idx += 512) {
    const int fg = idx >> 6, ln = idx & 63;
    const int mm = ln & 15;
    const int kc = fg >> 3, nt = fg & 7;
    short8 v;
    #pragma unroll
    for (int j = 0; j < 8; ++j) {
      const int khw = kc * 32 + (ln >> 4) * 8 + j;
      const int ctrue = ((khw & 7) << 4) | (khw >> 3);
      v[j] = (short)f2bf(w2[ctrue * NHID + nt * 16 + mm]);
    }
    w2f[idx] = v;
  }

  const int jc = t & 63;                          // u32 col in kstore order
  const int quarter = t >> 6;                     // rows [16*quarter, +16)

  const int nbt = (E + EB2 - 1) / EB2;
  __syncthreads();

  // preload first tile's index data
  int2 sv = make_int2(0, -1);
  {
    const int tile0 = blockIdx.x;
    const int gb = tile0 * EB2;
    if (t < EB2) {
      const int e = gb + t;
      if (tile0 < nbt && e < E) sv = sorted[e];
    } else if (t == EB2) {
      sv.y = (tile0 < nbt && gb > 0) ? sorted[gb - 1].y : -2;
    } else if (t == EB2 + 1) {
      sv.y = (tile0 < nbt && gb + EB2 < E) ? sorted[gb + EB2].y : -2;
    }
  }

  for (int tile = blockIdx.x; tile < nbt; tile += gridDim.x) {
    if (t < EB2) { esS[t] = sv.x; edS[t] = sv.y; }
    else if (t == EB2) pn[0] = sv.y;
    else if (t == EB2 + 1) pn[1] = sv.y;
    __syncthreads();   // A

    if (w == 0) {
      int d0 = edS[lane];
      int dp0 = (lane == 0) ? -9 : edS[lane - 1];
      unsigned long long mk0 = __ballot(lane == 0 || d0 != dp0);
      int d1 = edS[64 + lane];
      int dp1 = edS[63 + lane];
      unsigned long long mk1 = __ballot(d1 != dp1);
      if (lane == 0) { maskS[0] = mk0; maskS[1] = mk1; }
    }

    // layer 1
    floatx4 acc[8];
    #pragma unroll
    for (int nt = 0; nt < 8; ++nt) { floatx4 z = {0.f, 0.f, 0.f, 0.f}; acc[nt] = z; }
    short8 a1 = {0, 0, 0, 0, 0, 0, 0, 0};
    if (q == 0) {
      const int e = 16 * w + m;
      const int si = esS[e];
      const int d0 = edS[e];
      const int di = (d0 < 0) ? 0 : d0;
      float xi0 = x[di * 3], xi1 = x[di * 3 + 1], xi2 = x[di * 3 + 2];
      float dd0 = x[si * 3] - xi0, dd1 = x[si * 3 + 1] - xi1, dd2 = x[si * 3 + 2] - xi2;
      union { short8 s; uint4 u; } cv;
      cv.u = make_uint4(pkbf(xi0, xi1), pkbf(xi2, dd0), pkbf(dd1, dd2), 0u);
      a1 = cv.s;
    }
    #pragma unroll
    for (int nt = 0; nt < 8; ++nt)
      acc[nt] = __builtin_amdgcn_mfma_f32_16x16x32_bf16(a1, bf1[nt], acc[nt], 0, 0, 0);

    #pragma unroll
    for (int r = 0; r < 4; ++r) {
      union { short8 s; uint4 u; } cv;
      cv.u = make_uint4(
        pkbf(fmaxf(acc[0][r] + b1c[0], 0.f), fmaxf(acc[1][r] + b1c[1], 0.f)),
        pkbf(fmaxf(acc[2][r] + b1c[2], 0.f), fmaxf(acc[3][r] + b1c[3], 0.f)),
        pkbf(fmaxf(acc[4][r] + b1c[4], 0.f), fmaxf(acc[5][r] + b1c[5], 0.f)),
        pkbf(fmaxf(acc[6][r] + b1c[6], 0.f), fmaxf(acc[7][r] + b1c[7], 0.f)));
      *(short8*)(&us[(16 * w + q * 4 + r) * PADROW + m * 8]) = cv.s;
    }
    __syncthreads();   // B

    // layer 2
    #pragma unroll
    for (int nt = 0; nt < 8; ++nt) { floatx4 z = {0.f, 0.f, 0.f, 0.f}; acc[nt] = z; }
    #pragma unroll
    for (int kc = 0; kc < 4; ++kc) {
      short8 a = *(const short8*)(&us[(16 * w + m) * PADROW + kc * 32 + q * 8]);
      #pragma unroll
      for (int nt = 0; nt < 8; ++nt)
        acc[nt] = __builtin_amdgcn_mfma_f32_16x16x32_bf16(a, w2f[(kc * 8 + nt) * 64 + lane],
                                                          acc[nt], 0, 0, 0);
    }
    __syncthreads();   // C

    #pragma unroll
    for (int r = 0; r < 4; ++r) {
      union { short8 s; uint4 u; } cv;
      cv.u = make_uint4(
        pkbf(fmaxf(acc[0][r] + b2c[0], 0.f), fmaxf(acc[1][r] + b2c[1], 0.f)),
        pkbf(fmaxf(acc[2][r] + b2c[2], 0.f), fmaxf(acc[3][r] + b2c[3], 0.f)),
        pkbf(fmaxf(acc[4][r] + b2c[4], 0.f), fmaxf(acc[5][r] + b2c[5], 0.f)),
        pkbf(fmaxf(acc[6][r] + b2c[6], 0.f), fmaxf(acc[7][r] + b2c[7], 0.f)));
      *(short8*)(&us[(16 * w + q * 4 + r) * PADROW + m * 8]) = cv.s;
    }
    __syncthreads();   // D: hS ready

    // prefetch next tile's index data
    {
      const int tn = tile + gridDim.x;
      const int gb = tn * EB2;
      int2 nv = make_int2(0, -1);
      if (t < EB2) {
        const int e = gb + t;
        if (tn < nbt && e < E) nv = sorted[e];
      } else if (t == EB2) {
        nv.y = (tn < nbt && gb > 0) ? sorted[gb - 1].y : -2;
      } else if (t == EB2 + 1) {
        nv.y = (tn < nbt && gb + EB2 < E) ? sorted[gb + EB2].y : -2;
      }
      sv = nv;
    }

    // stage 3 pass 1: per-quarter partials; contained runs stored directly
    int os = -1, onxt = 0, od = -1; unsigned int opart = 0;
    {
      const unsigned long long mk0 = maskS[0], mk1 = maskS[1];
      const int prevd = pn[0], nextd = pn[1];
      const int r0 = quarter * 16, r1 = r0 + 16;
      const unsigned int* us32 = (const unsigned int*)us;
      int s;
      if (r0 < 64) {
        s = 63 - __builtin_clzll(mk0 & (~0ULL >> (63 - r0)));
      } else {
        unsigned long long hm = mk1 & (~0ULL >> (127 - r0));
        s = hm ? 127 - __builtin_clzll(hm) : 63 - __builtin_clzll(mk0);
      }
      while (s < r1) {
        int nxt;
        if (s < 63) {
          unsigned long long ab = mk0 & (~0ULL << (s + 1));
          if (ab) nxt = __builtin_ffsll((long long)ab) - 1;
          else    nxt = mk1 ? 64 + __builtin_ffsll((long long)mk1) - 1 : 128;
        } else if (s == 63) {
          nxt = mk1 ? 64 + __builtin_ffsll((long long)mk1) - 1 : 128;
        } else if (s < 127) {
          unsigned long long ab = mk1 & (~0ULL << (s - 63));
          nxt = ab ? 64 + __builtin_ffsll((long long)ab) - 1 : 128;
        } else nxt = 128;

        const int lo = (s > r0) ? s : r0;
        const int hi = (nxt < r1) ? nxt : r1;
        unsigned int run = 0;
        for (int r = lo; r < hi; ++r)
          run = pkmax(run, us32[r * (PADROW >> 1) + jc]);

        if (s < r0) {
          pmS[quarter][jc] = run;                 // run covering this quarter's r0
        } else if (nxt <= r1) {
          const int d = edS[s];
          if (d >= 0) {
            const bool bnd = (s == 0 && prevd == d) || (nxt == 128 && nextd == d);
            unsigned int* ap = aggu + (size_t)d * 64 + jc;
            if (!bnd) *ap = run;
            else if (run) casmax(ap, run);
          }
        } else {                                  // owner of a spanning run
          os = s; onxt = nxt; od = edS[s]; opart = run;
        }
        s = nxt;
      }
    }
    __syncthreads();   // E: pmS ready

    // stage 3 pass 2: owners combine partials and write once
    if (os >= 0 && od >= 0) {
      const int endq = (onxt - 1) >> 4;
      #pragma unroll 4
      for (int qq = quarter + 1; qq <= endq; ++qq)
        opart = pkmax(opart, pmS[qq][jc]);
      const bool bnd = (os == 0 && pn[0] == od) || (onxt == 128 && pn[1] == od);
      unsigned int* ap = aggu + (size_t)od * 64 + jc;
      if (!bnd) *ap = opart;
      else if (opart) casmax(ap, opart);
    }
    __syncthreads();   // F
  }
}

// ---------------- fallback: atomic edge kernel (small ws) ----------------

__global__ __launch_bounds__(256, 2) void edge_atomic_kernel(
    const float* __restrict__ x, const int* __restrict__ ei,
    const float* __restrict__ w1, const float* __restrict__ b1,
    const float* __restrict__ w2, const float* __restrict__ b2,
    unsigned int* aggu, const int* __restrict__ flag64, int N, int E) {
  __shared__ unsigned short uA[EB * PADROW];
  __shared__ float w1s[6 * NHID];
  __shared__ float b1s[NHID], b2s[NHID];
  __shared__ int es[EB], ed[EB];

  const int t = threadIdx.x;
  const int lane = t & 63;
  const int w = t >> 6;
  const int m = lane & 15;
  const int q = lane >> 4;

  for (int i = t; i < 6 * NHID; i += 256) w1s[i] = w1[i];
  if (t < NHID) { b1s[t] = b1[t]; b2s[t] = b2[t]; }

  short8 bf[32];
  load_bfrags(w2, bf, m, q);

  const bool is64 = (flag64[0] != 0);
  const int nb = (E + EB - 1) / EB;

  for (int batch = blockIdx.x; batch < nb; batch += gridDim.x) {
    const int gbase = batch * EB;
    if (t < EB) {
      int e = gbase + t;
      es[t] = (e < E) ? (is64 ? ei[2 * e] : ei[e]) : 0;
    } else if (t < 2 * EB) {
      int tt = t - EB;
      int e = gbase + tt;
      ed[tt] = (e < E) ? (is64 ? ei[2 * E + 2 * e] : ei[E + e]) : 0;
    }
    __syncthreads();
    {
      const int e = t >> 2;
      const int c0 = (t & 3) * 32;
      const int si = es[e], di = ed[e];
      float xi0 = x[di * 3], xi1 = x[di * 3 + 1], xi2 = x[di * 3 + 2];
      float msg[6];
      msg[0] = xi0; msg[1] = xi1; msg[2] = xi2;
      msg[3] = x[si * 3] - xi0; msg[4] = x[si * 3 + 1] - xi1; msg[5] = x[si * 3 + 2] - xi2;
      unsigned int* d32 = (unsigned int*)uA;
      const int base32 = (e * PADROW + c0) >> 1;
      #pragma unroll
      for (int cc = 0; cc < 32; cc += 2) {
        float u0 = b1s[c0 + cc], u1 = b1s[c0 + cc + 1];
        #pragma unroll
        for (int d = 0; d < 6; ++d) {
          u0 += msg[d] * w1s[d * NHID + c0 + cc];
          u1 += msg[d] * w1s[d * NHID + c0 + cc + 1];
        }
        d32[base32 + (cc >> 1)] = pack2(fmaxf(u0, 0.f), fmaxf(u1, 0.f));
      }
    }
    __syncthreads();

    floatx4 acc[8];
    #pragma unroll
    for (int nt = 0; nt < 8; ++nt) { floatx4 z = {0.f, 0.f, 0.f, 0.f}; acc[nt] = z; }
    mfma_block(uA, bf, acc, w, m, q);

    #pragma unroll
    for (int nt = 0; nt < 8; ++nt) {
      const int c = nt * 16 + m;
      const float bb = b2s[c];
      const int kst = m * 8 + nt;
      #pragma unroll
      for (int r = 0; r < 4; ++r) {
        const int erow = 16 * w + q * 4 + r;
        if (gbase + erow < E) {
          float hb = acc[nt][r] + bb;
          if (hb > 0.f) {
            unsigned int v = (unsigned int)f2bf(hb);
            casmax(aggu + (size_t)ed[erow] * 64 + (kst >> 1), v << (16 * (kst & 1)));
          }
        }
      }
    }
    __syncthreads();
  }
}

// ---------------- fused node MLPs: enc (w3) + dec (w4,w5), agg16 input ----------------
// R9 structure (barriers B0/B1/B2/B3) — R10's barrier removal regressed.

__global__ __launch_bounds__(256, 2) void encdec_kernel(
    const float* __restrict__ w3, const float* __restrict__ b3,
    const float* __restrict__ w4, const float* __restrict__ b4,
    const float* __restrict__ w5, const float* __restrict__ b5,
    const float* __restrict__ pos, const unsigned short* __restrict__ agg16,
    float* __restrict__ out, int N) {
  __shared__ unsigned short uA[EB * PADROW];
  __shared__ short8 w4f[2048];                    // k-permuted w4 frags
  __shared__ float w5s[NHID * 3];

  const int t = threadIdx.x;
  const int lane = t & 63;
  const int w = t >> 6;
  const int m = lane & 15;
  const int q = lane >> 4;

  float b3c[8], b4c[8];
  #pragma unroll
  for (int nt = 0; nt < 8; ++nt) { b3c[nt] = b3[nt * 16 + m]; b4c[nt] = b4[nt * 16 + m]; }

  short8 bf3[32];
  load_bfrags_perm(w3, bf3, m, q);                // k-permuted (agg16 is kstore-ordered)

  for (int idx = t; idx < 2048; idx += 256) {
    const int fg = idx >> 6, ln = idx & 63;
    const int mm = ln & 15;
    const int kc = fg >> 3, nt = fg & 7;
    short8 v;
    #pragma unroll
    for (int j = 0; j < 8; ++j) {
      const int khw = kc * 32 + (ln >> 4) * 8 + j;
      const int ctrue = ((khw & 7) << 4) | (khw >> 3);
      v[j] = (short)f2bf(w4[ctrue * NHID + nt * 16 + mm]);
    }
    w4f[idx] = v;
  }
  for (int i = t; i < NHID * 3; i += 256) w5s[i] = w5[i];
  const float b50 = b5[0], b51 = b5[1], b52 = b5[2];

  const int ch = t & 15;
  const int rr = t >> 4;
  const int nb = (N + EB - 1) / EB;
  __syncthreads();

  uint4 rv[4];
  const uint4 uz = make_uint4(0u, 0u, 0u, 0u);
  {
    const int b0 = blockIdx.x;
    #pragma unroll
    for (int k = 0; k < 4; ++k) {
      const int node = b0 * EB + rr + 16 * k;
      rv[k] = (b0 < nb && node < N) ? ((const uint4*)agg16)[(size_t)node * 16 + ch] : uz;
    }
  }

  for (int batch = blockIdx.x; batch < nb; batch += gridDim.x) {
    const int base = batch * EB;
    #pragma unroll
    for (int k = 0; k < 4; ++k)
      *(uint4*)(&uA[(rr + 16 * k) * PADROW + ch * 8]) = rv[k];
    __syncthreads();   // B0

    {
      const int nxb = batch + gridDim.x;
      #pragma unroll
      for (int k = 0; k < 4; ++k) {
        const int node = nxb * EB + rr + 16 * k;
        rv[k] = (nxb < nb && node < N) ? ((const uint4*)agg16)[(size_t)node * 16 + ch] : uz;
      }
    }

    floatx4 acc[8];
    #pragma unroll
    for (int nt = 0; nt < 8; ++nt) { floatx4 z = {0.f, 0.f, 0.f, 0.f}; acc[nt] = z; }
    mfma_block(uA, bf3, acc, w, m, q);
    __syncthreads();   // B1

    #pragma unroll
    for (int r = 0; r < 4; ++r) {
      union { short8 s; uint4 u; } cv;
      cv.u = make_uint4(
        pkbf(acc[0][r] + b3c[0], acc[1][r] + b3c[1]),
        pkbf(acc[2][r] + b3c[2], acc[3][r] + b3c[3]),
        pkbf(acc[4][r] + b3c[4], acc[5][r] + b3c[5]),
        pkbf(acc[6][r] + b3c[6], acc[7][r] + b3c[7]));
      *(short8*)(&uA[(16 * w + q * 4 + r) * PADROW + m * 8]) = cv.s;
    }
    __syncthreads();   // B2

    #pragma unroll
    for (int nt = 0; nt < 8; ++nt) { floatx4 z = {0.f, 0.f, 0.f, 0.f}; acc[nt] = z; }
    #pragma unroll
    for (int kc = 0; kc < 4; ++kc) {
      short8 a = *(const short8*)(&uA[(16 * w + m) * PADROW + kc * 32 + q * 8]);
      #pragma unroll
      for (int nt = 0; nt < 8; ++nt)
        acc[nt] = __builtin_amdgcn_mfma_f32_16x16x32_bf16(a, w4f[(kc * 8 + nt) * 64 + lane],
                                                          acc[nt], 0, 0, 0);
    }

    float p[4][3];
    #pragma unroll
    for (int r = 0; r < 4; ++r) { p[r][0] = 0.f; p[r][1] = 0.f; p[r][2] = 0.f; }
    #pragma unroll
    for (int nt = 0; nt < 8; ++nt) {
      const int c = nt * 16 + m;
      const float bb = b4c[nt];
      const float w50 = w5s[c * 3], w51 = w5s[c * 3 + 1], w52 = w5s[c * 3 + 2];
      #pragma unroll
      for (int r = 0; r < 4; ++r) {
        float tv = fmaxf(acc[nt][r] + bb, 0.f);
        p[r][0] += tv * w50; p[r][1] += tv * w51; p[r][2] += tv * w52;
      }
    }
    #pragma unroll
    for (int off = 8; off >= 1; off >>= 1) {
      #pragma unroll
      for (int r = 0; r < 4; ++r) {
        p[r][0] += __shfl_xor(p[r][0], off, 16);
        p[r][1] += __shfl_xor(p[r][1], off, 16);
        p[r][2] += __shfl_xor(p[r][2], off, 16);
      }
    }
    if (m == 0) {
      #pragma unroll
      for (int r = 0; r < 4; ++r) {
        const int node = base + 16 * w + q * 4 + r;
        if (node < N) {
          out[node * 3]     = pos[node * 3]     + 0.1f * tanhf(p[r][0] + b50);
          out[node * 3 + 1] = pos[node * 3 + 1] + 0.1f * tanhf(p[r][1] + b51);
          out[node * 3 + 2] = pos[node * 3 + 2] + 0.1f * tanhf(p[r][2] + b52);
        }
      }
    }
    __syncthreads();   // B3
  }
}

extern "C" void kernel_launch(void* const* d_in, const int* in_sizes, int n_in,
                              void* d_out, int out_size, void* d_ws, size_t ws_size,
                              hipStream_t stream) {
  const float* x   = (const float*)d_in[0];
  const float* pos = (const float*)d_in[1];
  const int*   ei  = (const int*)d_in[2];
  const float* w1  = (const float*)d_in[3];
  const float* b1  = (const float*)d_in[4];
  const float* w2  = (const float*)d_in[5];
  const float* b2  = (const float*)d_in[6];
  const float* w3  = (const float*)d_in[7];
  const float* b3  = (const float*)d_in[8];
  const float* w4  = (const float*)d_in[9];
  const float* b4  = (const float*)d_in[10];
  const float* w5  = (const float*)d_in[11];
  const float* b5  = (const float*)d_in[12];
  float* out = (float*)d_out;

  const int N = in_sizes[0] / 3;
  const int E = in_sizes[2] / 2;
  const int nbuck = (N + 255) >> 8;

  char* ws = (char*)d_ws;
  unsigned short* agg16 = (unsigned short*)ws;                // N*128 u16 (kstore order)
  const size_t aggB = (size_t)N * NHID * sizeof(unsigned short);
  int2* mid    = (int2*)(ws + aggB);
  int2* sorted = (int2*)(ws + aggB + (size_t)E * 8);
  int*  mat    = (int*)(ws + aggB + (size_t)E * 16);
  int*  btot   = mat + (size_t)nbuck * PB;
  int*  bstart = btot + nbuck;
  unsigned int* cnt = (unsigned int*)(bstart + 513);
  const size_t needed = aggB + (size_t)E * 16 + ((size_t)nbuck * PB + nbuck + 513 + 8) * 4;

  if (ws_size >= needed && nbuck <= 511 && E >= 64) {
    hipMemsetAsync(cnt, 0, sizeof(unsigned int), stream);
    sort_fused<<<PB, 1024, 0, stream>>>(ei, E, nbuck, mat, btot, bstart,
                                        mid, sorted, (float4*)agg16, N * 16, cnt);
    edge_sorted_kernel<<<512, 512, 0, stream>>>(x, sorted, w1, b1, w2, b2,
                                                (unsigned int*)agg16, N, E);
  } else {
    int* flag2 = (int*)(ws + aggB);
    zero_detect_kernel<<<2048, 256, 0, stream>>>((float4*)agg16, N * 16, ei, flag2);
    edge_atomic_kernel<<<512, 256, 0, stream>>>(x, ei, w1, b1, w2, b2,
                                                (unsigned int*)agg16, flag2, N, E);
  }
  encdec_kernel<<<512, 256, 0, stream>>>(w3, b3, w4, b4, w5, b5, pos, agg16, out, N);
}

// Round 14
// 346.339 us; speedup vs baseline: 2.4614x; 2.4614x over previous
//
#include <hip/hip_runtime.h>
#include <hip/hip_bf16.h>

typedef __attribute__((ext_vector_type(8))) short short8;
typedef __attribute__((ext_vector_type(4))) float floatx4;
typedef __attribute__((ext_vector_type(2))) unsigned short ushortx2;

#define NHID 128
#define PADROW 136   // u16 row stride: 272B, 16B-aligned b128, benign banking
#define EB 64        // nodes per tile (encdec / fallback)
#define EB2 128      // edges per tile (edge_sorted)
#define PB 256       // partition blocks for the 2-level sort

__device__ __forceinline__ unsigned short f2bf(float x) {
  unsigned int u = __float_as_uint(x);
  u += 0x7FFFu + ((u >> 16) & 1u);          // RNE
  return (unsigned short)(u >> 16);
}

__device__ __forceinline__ unsigned int pkbf(float a, float b) {
  __hip_bfloat162 h = __float22bfloat162_rn(make_float2(a, b));
  union { __hip_bfloat162 h; unsigned int u; } cv;
  cv.h = h;
  return cv.u;
}

__device__ __forceinline__ unsigned int pack2(float a, float b) {
  return (unsigned int)f2bf(a) | ((unsigned int)f2bf(b) << 16);
}

// packed u16 max (v_pk_max_u16)
__device__ __forceinline__ unsigned int pkmax(unsigned int a, unsigned int b) {
  union { unsigned int u; ushortx2 v; } x, y;
  x.u = a; y.u = b;
  x.v = __builtin_elementwise_max(x.v, y.v);
  return x.u;
}

__device__ __forceinline__ void casmax(unsigned int* ap, unsigned int run) {
  unsigned int old = *ap;
  while (true) {
    unsigned int mx = pkmax(old, run);
    if (mx == old) break;
    unsigned int got = atomicCAS(ap, old, mx);
    if (got == old) break;
    old = got;
  }
}

// all-wave inline int64 probe: odd int32 slots all-zero <=> int64 edge_index
__device__ __forceinline__ bool detect64(const int* __restrict__ ei) {
  unsigned long long b = __ballot(ei[2 * (threadIdx.x & 63) + 1] != 0);
  return b == 0ULL;
}

// 32 loop-invariant B-fragments of a 128x128 row-major f32 weight (registers), natural k.
__device__ __forceinline__ void load_bfrags(const float* __restrict__ wmat,
                                            short8* bf, int m, int q) {
  #pragma unroll
  for (int kc = 0; kc < 4; ++kc) {
    #pragma unroll
    for (int nt = 0; nt < 8; ++nt) {
      short8 v;
      #pragma unroll
      for (int j = 0; j < 8; ++j)
        v[j] = (short)f2bf(wmat[(kc * 32 + q * 8 + j) * NHID + nt * 16 + m]);
      bf[kc * 8 + nt] = v;
    }
  }
}

// same but k-permuted: B[khw][n] = w[pi(khw)][n], pi(k) = ((k&7)<<4)|(k>>3)
__device__ __forceinline__ void load_bfrags_perm(const float* __restrict__ wmat,
                                                 short8* bf, int m, int q) {
  #pragma unroll
  for (int kc = 0; kc < 4; ++kc) {
    #pragma unroll
    for (int nt = 0; nt < 8; ++nt) {
      short8 v;
      #pragma unroll
      for (int j = 0; j < 8; ++j) {
        const int khw = kc * 32 + q * 8 + j;
        const int ctrue = ((khw & 7) << 4) | (khw >> 3);
        v[j] = (short)f2bf(wmat[ctrue * NHID + nt * 16 + m]);
      }
      bf[kc * 8 + nt] = v;
    }
  }
}

__device__ __forceinline__ void mfma_block(const unsigned short* uA,
                                           const short8* bf, floatx4* acc,
                                           int w, int m, int q) {
  #pragma unroll
  for (int kc = 0; kc < 4; ++kc) {
    short8 a = *(const short8*)(uA + (16 * w + m) * PADROW + kc * 32 + q * 8);
    #pragma unroll
    for (int nt = 0; nt < 8; ++nt)
      acc[nt] = __builtin_amdgcn_mfma_f32_16x16x32_bf16(a, bf[kc * 8 + nt],
                                                        acc[nt], 0, 0, 0);
  }
}

// fallback-path zero (agg16) + detect->flag
__global__ void zero_detect_kernel(float4* __restrict__ p, int n4,
                                   const int* __restrict__ ei, int* __restrict__ flag) {
  if (blockIdx.x == 0 && threadIdx.x < 64) {
    unsigned long long b = __ballot(ei[2 * threadIdx.x + 1] != 0);
    if (threadIdx.x == 0) flag[0] = (b == 0ULL) ? 1 : 0;
  }
  int i = blockIdx.x * blockDim.x + threadIdx.x;
  int stride = gridDim.x * blockDim.x;
  float4 z = make_float4(0.f, 0.f, 0.f, 0.f);
  for (; i < n4; i += stride) p[i] = z;
}

// ---------------- 2-level counting sort by dst (no global atomics) ----------------
// Split pipeline (R11): grid-barrier fusion regressed badly (R12: 230 µs @ 4 waves/CU;
// R13: 570 µs @ 16 waves/CU — global phase lockstep + hot counter line, not occupancy).

// A1: per-partition LDS histogram over coarse buckets (dst>>8); tail blocks zero agg16
__global__ __launch_bounds__(256) void part_hist(const int* __restrict__ ei,
                                                 int* __restrict__ mat, int E, int nbuck,
                                                 float4* __restrict__ aggz, int n4) {
  const int bl = blockIdx.x, t = threadIdx.x;
  if (bl >= PB) {
    int i = (bl - PB) * 256 + t;
    const int st = (gridDim.x - PB) * 256;
    float4 z = make_float4(0.f, 0.f, 0.f, 0.f);
    for (; i < n4; i += st) aggz[i] = z;
    return;
  }
  __shared__ int hist[512];
  const bool is64 = detect64(ei);
  for (int i = t; i < nbuck; i += 256) hist[i] = 0;
  __syncthreads();
  const int chunk = (E + PB - 1) / PB;
  const int lo = bl * chunk;
  const int hi = min(lo + chunk, E);
  for (int i = lo + t; i < hi; i += 256) {
    int d = is64 ? ei[2 * E + 2 * i] : ei[E + i];
    atomicAdd(&hist[d >> 8], 1);
  }
  __syncthreads();
  for (int bu = t; bu < nbuck; bu += 256) mat[bu * PB + bl] = hist[bu];
}

// A2: per-bucket exclusive scan over the PB partitions (in place) + bucket totals
__global__ __launch_bounds__(256) void scan_rows(int* __restrict__ mat,
                                                 int* __restrict__ btot, int nbuck) {
  __shared__ int sh[256];
  const int bu = blockIdx.x, t = threadIdx.x;
  const int v = mat[bu * PB + t];
  sh[t] = v;
  __syncthreads();
  for (int off = 1; off < 256; off <<= 1) {
    int x = (t >= off) ? sh[t - off] : 0;
    __syncthreads();
    sh[t] += x;
    __syncthreads();
  }
  mat[bu * PB + t] = sh[t] - v;
  if (t == 255) btot[bu] = sh[255];
}

// A3: scatter into coarse-bucket regions; bucket starts scanned in-LDS from btot.
// 512 threads (was 256): 256-block grid is only ~4 waves/CU at 256 thr — latency-
// starved (R12 lesson). Scan section guarded to t<256 (pattern validated in R13).
__global__ __launch_bounds__(512) void part_scatter(const int* __restrict__ ei,
                                                    const int* __restrict__ mat,
                                                    const int* __restrict__ btot,
                                                    int* __restrict__ bstart,
                                                    int2* __restrict__ mid, int E, int nbuck) {
  __shared__ int off[512];
  __shared__ int bsS[512];
  const bool is64 = detect64(ei);
  const int bl = blockIdx.x, t = threadIdx.x;
  const int o0 = (t < 256 && t < nbuck) ? btot[t] : 0;
  const int o1 = (t < 256 && t + 256 < nbuck) ? btot[t + 256] : 0;
  if (t < 256) { bsS[t] = o0; bsS[t + 256] = o1; }
  __syncthreads();
  for (int o = 1; o < 256; o <<= 1) {
    int x0 = (t >= o && t < 256) ? bsS[t - o] : 0;
    int x1 = (t >= o && t < 256) ? bsS[256 + t - o] : 0;
    __syncthreads();
    if (t < 256) { bsS[t] += x0; bsS[256 + t] += x1; }
    __syncthreads();
  }
  const int tot0 = bsS[255];
  if (t < 256) bsS[256 + t] += tot0;
  __syncthreads();
  if (t < 256) {
    const int ex0 = bsS[t] - o0;
    const int ex1 = bsS[256 + t] - o1;
    if (bl == 0) { bstart[t] = ex0; bstart[256 + t] = ex1; }
    off[t]       = ex0 + ((t < nbuck) ? mat[t * PB + bl] : 0);
    off[256 + t] = ex1 + ((t + 256 < nbuck) ? mat[(t + 256) * PB + bl] : 0);
  }
  __syncthreads();
  const int chunk = (E + PB - 1) / PB;
  const int lo = bl * chunk;
  const int hi = min(lo + chunk, E);
  for (int i = lo + t; i < hi; i += 512) {
    int s = is64 ? ei[2 * i]         : ei[i];
    int d = is64 ? ei[2 * E + 2 * i] : ei[E + i];
    int p = atomicAdd(&off[d >> 8], 1);
    mid[p] = make_int2(s, d);
  }
}

// B: per-bucket counting sort by exact dst (256 local nodes), L2-resident traffic.
// 512 threads (was 256) for the same latency-starvation reason.
__global__ __launch_bounds__(512) void bucket_sort(const int2* __restrict__ mid,
                                                   const int* __restrict__ bstart,
                                                   int2* __restrict__ sorted) {
  __shared__ int h[256], cnt[256];
  const int bu = blockIdx.x, t = threadIdx.x;
  const int lo = bstart[bu], hi = bstart[bu + 1];
  if (t < 256) { h[t] = 0; cnt[t] = 0; }
  __syncthreads();
  for (int i = lo + t; i < hi; i += 512) atomicAdd(&h[mid[i].y & 255], 1);
  __syncthreads();
  const int v = (t < 256) ? h[t] : 0;
  for (int off = 1; off < 256; off <<= 1) {
    int x = (t >= off && t < 256) ? h[t - off] : 0;
    __syncthreads();
    if (t < 256) h[t] += x;
    __syncthreads();
  }
  const int excl = (t < 256) ? h[t] - v : 0;
  __syncthreads();
  if (t < 256) h[t] = excl;
  __syncthreads();
  for (int i = lo + t; i < hi; i += 512) {
    int2 e = mid[i];
    const int dl = e.y & 255;
    const int p = lo + h[dl] + atomicAdd(&cnt[dl], 1);
    sorted[p] = e;
  }
}

// ---------------- fused edge MLP (both layers MFMA) + segmented max ----------------
// R9 structure (barriers A/B/C/D/E/F): barrier lockstep is a beneficial scheduling
// fence — R10's barrier removal raised VGPR 60->92 and regressed 178->260 µs.
// agg16: u16[N][128] in kstore (k-permuted) order. Stage-3: two-pass LDS run merge.

__global__ __launch_bounds__(512, 2) void edge_sorted_kernel(
    const float* __restrict__ x, const int2* __restrict__ sorted,
    const float* __restrict__ w1, const float* __restrict__ b1,
    const float* __restrict__ w2, const float* __restrict__ b2,
    unsigned int* aggu, int N, int E) {
  __shared__ unsigned short us[EB2 * PADROW];     // uA then hS (bf16)
  __shared__ short8 w2f[2048];                    // 32 frags x 64 lanes, k-permuted
  __shared__ int esS[EB2], edS[EB2];
  __shared__ int pn[2];                           // dst before / after tile (-2 = none)
  __shared__ unsigned long long maskS[2];         // run-start bitmask
  __shared__ unsigned int pmS[8][64];             // per-quarter partial of run covering r0

  const int t = threadIdx.x;
  const int lane = t & 63;
  const int w = t >> 6;                           // wave 0..7
  const int m = lane & 15;
  const int q = lane >> 4;

  float b1c[8], b2c[8];
  #pragma unroll
  for (int nt = 0; nt < 8; ++nt) { b1c[nt] = b1[nt * 16 + m]; b2c[nt] = b2[nt * 16 + m]; }

  short8 bf1[8];
  #pragma unroll
  for (int nt = 0; nt < 8; ++nt) {
    short8 v;
    #pragma unroll
    for (int j = 0; j < 8; ++j)
      v[j] = (q == 0 && j < 6) ? (short)f2bf(w1[j * NHID + nt * 16 + m]) : (short)0;
    bf1[nt] = v;
  }

  for (int idx = t; idx < 2048; idx += 512) {
    const int fg = idx >> 6, ln = idx & 63;
    const int mm = ln & 15;
    const int kc = fg >> 3, nt = fg & 7;
    short8 v;
    #pragma unroll
    for (int j = 0; j < 8; ++j) {
      const int khw = kc * 32 + (ln >> 4) * 8 + j;
      const int ctrue = ((khw & 7) << 4) | (khw >> 3);
      v[j] = (short)f2bf(w2[ctrue * NHID + nt * 16 + mm]);
    }
    w2f[idx] = v;
  }

  const int jc = t & 63;                          // u32 col in kstore order
  const int quarter = t >> 6;                     // rows [16*quarter, +16)

  const int nbt = (E + EB2 - 1) / EB2;
  __syncthreads();

  // preload first tile's index data
  int2 sv = make_int2(0, -1);
  {
    const int tile0 = blockIdx.x;
    const int gb = tile0 * EB2;
    if (t < EB2) {
      const int e = gb + t;
      if (tile0 < nbt && e < E) sv = sorted[e];
    } else if (t == EB2) {
      sv.y = (tile0 < nbt && gb > 0) ? sorted[gb - 1].y : -2;
    } else if (t == EB2 + 1) {
      sv.y = (tile0 < nbt && gb + EB2 < E) ? sorted[gb + EB2].y : -2;
    }
  }

  for (int tile = blockIdx.x; tile < nbt; tile += gridDim.x) {
    if (t < EB2) { esS[t] = sv.x; edS[t] = sv.y; }
    else if (t == EB2) pn[0] = sv.y;
    else if (t == EB2 + 1) pn[1] = sv.y;
    __syncthreads();   // A

    if (w == 0) {
      int d0 = edS[lane];
      int dp0 = (lane == 0) ? -9 : edS[lane - 1];
      unsigned long long mk0 = __ballot(lane == 0 || d0 != dp0);
      int d1 = edS[64 + lane];
      int dp1 = edS[63 + lane];
      unsigned long long mk1 = __ballot(d1 != dp1);
      if (lane == 0) { maskS[0] = mk0; maskS[1] = mk1; }
    }

    // layer 1
    floatx4 acc[8];
    #pragma unroll
    for (int nt = 0; nt < 8; ++nt) { floatx4 z = {0.f, 0.f, 0.f, 0.f}; acc[nt] = z; }
    short8 a1 = {0, 0, 0, 0, 0, 0, 0, 0};
    if (q == 0) {
      const int e = 16 * w + m;
      const int si = esS[e];
      const int d0 = edS[e];
      const int di = (d0 < 0) ? 0 : d0;
      float xi0 = x[di * 3], xi1 = x[di * 3 + 1], xi2 = x[di * 3 + 2];
      float dd0 = x[si * 3] - xi0, dd1 = x[si * 3 + 1] - xi1, dd2 = x[si * 3 + 2] - xi2;
      union { short8 s; uint4 u; } cv;
      cv.u = make_uint4(pkbf(xi0, xi1), pkbf(xi2, dd0), pkbf(dd1, dd2), 0u);
      a1 = cv.s;
    }
    #pragma unroll
    for (int nt = 0; nt < 8; ++nt)
      acc[nt] = __builtin_amdgcn_mfma_f32_16x16x32_bf16(a1, bf1[nt], acc[nt], 0, 0, 0);

    #pragma unroll
    for (int r = 0; r < 4; ++r) {
      union { short8 s; uint4 u; } cv;
      cv.u = make_uint4(
        pkbf(fmaxf(acc[0][r] + b1c[0], 0.f), fmaxf(acc[1][r] + b1c[1], 0.f)),
        pkbf(fmaxf(acc[2][r] + b1c[2], 0.f), fmaxf(acc[3][r] + b1c[3], 0.f)),
        pkbf(fmaxf(acc[4][r] + b1c[4], 0.f), fmaxf(acc[5][r] + b1c[5], 0.f)),
        pkbf(fmaxf(acc[6][r] + b1c[6], 0.f), fmaxf(acc[7][r] + b1c[7], 0.f)));
      *(short8*)(&us[(16 * w + q * 4 + r) * PADROW + m * 8]) = cv.s;
    }
    __syncthreads();   // B

    // layer 2
    #pragma unroll
    for (int nt = 0; nt < 8; ++nt) { floatx4 z = {0.f, 0.f, 0.f, 0.f}; acc[nt] = z; }
    #pragma unroll
    for (int kc = 0; kc < 4; ++kc) {
      short8 a = *(const short8*)(&us[(16 * w + m) * PADROW + kc * 32 + q * 8]);
      #pragma unroll
      for (int nt = 0; nt < 8; ++nt)
        acc[nt] = __builtin_amdgcn_mfma_f32_16x16x32_bf16(a, w2f[(kc * 8 + nt) * 64 + lane],
                                                          acc[nt], 0, 0, 0);
    }
    __syncthreads();   // C

    #pragma unroll
    for (int r = 0; r < 4; ++r) {
      union { short8 s; uint4 u; } cv;
      cv.u = make_uint4(
        pkbf(fmaxf(acc[0][r] + b2c[0], 0.f), fmaxf(acc[1][r] + b2c[1], 0.f)),
        pkbf(fmaxf(acc[2][r] + b2c[2], 0.f), fmaxf(acc[3][r] + b2c[3], 0.f)),
        pkbf(fmaxf(acc[4][r] + b2c[4], 0.f), fmaxf(acc[5][r] + b2c[5], 0.f)),
        pkbf(fmaxf(acc[6][r] + b2c[6], 0.f), fmaxf(acc[7][r] + b2c[7], 0.f)));
      *(short8*)(&us[(16 * w + q * 4 + r) * PADROW + m * 8]) = cv.s;
    }
    __syncthreads();   // D: hS ready

    // prefetch next tile's index data
    {
      const int tn = tile + gridDim.x;
      const int gb = tn * EB2;
      int2 nv = make_int2(0, -1);
      if (t < EB2) {
        const int e = gb + t;
        if (tn < nbt && e < E) nv = sorted[e];
      } else if (t == EB2) {
        nv.y = (tn < nbt && gb > 0) ? sorted[gb - 1].y : -2;
      } else if (t == EB2 + 1) {
        nv.y = (tn < nbt && gb + EB2 < E) ? sorted[gb + EB2].y : -2;
      }
      sv = nv;
    }

    // stage 3 pass 1: per-quarter partials; contained runs stored directly
    int os = -1, onxt = 0, od = -1; unsigned int opart = 0;
    {
      const unsigned long long mk0 = maskS[0], mk1 = maskS[1];
      const int prevd = pn[0], nextd = pn[1];
      const int r0 = quarter * 16, r1 = r0 + 16;
      const unsigned int* us32 = (const unsigned int*)us;
      int s;
      if (r0 < 64) {
        s = 63 - __builtin_clzll(mk0 & (~0ULL >> (63 - r0)));
      } else {
        unsigned long long hm = mk1 & (~0ULL >> (127 - r0));
        s = hm ? 127 - __builtin_clzll(hm) : 63 - __builtin_clzll(mk0);
      }
      while (s < r1) {
        int nxt;
        if (s < 63) {
          unsigned long long ab = mk0 & (~0ULL << (s + 1));
          if (ab) nxt = __builtin_ffsll((long long)ab) - 1;
          else    nxt = mk1 ? 64 + __builtin_ffsll((long long)mk1) - 1 : 128;
        } else if (s == 63) {
          nxt = mk1 ? 64 + __builtin_ffsll((long long)mk1) - 1 : 128;
        } else if (s < 127) {
          unsigned long long ab = mk1 & (~0ULL << (s - 63));
          nxt = ab ? 64 + __builtin_ffsll((long long)ab) - 1 : 128;
        } else nxt = 128;

        const int lo = (s > r0) ? s : r0;
        const int hi = (nxt < r1) ? nxt : r1;
        unsigned int run = 0;
        for (int r = lo; r < hi; ++r)
          run = pkmax(run, us32[r * (PADROW >> 1) + jc]);

        if (s < r0) {
          pmS[quarter][jc] = run;                 // run covering this quarter's r0
        } else if (nxt <= r1) {
          const int d = edS[s];
          if (d >= 0) {
            const bool bnd = (s == 0 && prevd == d) || (nxt == 128 && nextd == d);
            unsigned int* ap = aggu + (size_t)d * 64 + jc;
            if (!bnd) *ap = run;
            else if (run) casmax(ap, run);
          }
        } else {                                  // owner of a spanning run
          os = s; onxt = nxt; od = edS[s]; opart = run;
        }
        s = nxt;
      }
    }
    __syncthreads();   // E: pmS ready

    // stage 3 pass 2: owners combine partials and write once
    if (os >= 0 && od >= 0) {
      const int endq = (onxt - 1) >> 4;
      #pragma unroll 4
      for (int qq = quarter + 1; qq <= endq; ++qq)
        opart = pkmax(opart, pmS[qq][jc]);
      const bool bnd = (os == 0 && pn[0] == od) || (onxt == 128 && pn[1] == od);
      unsigned int* ap = aggu + (size_t)od * 64 + jc;
      if (!bnd) *ap = opart;
      else if (opart) casmax(ap, opart);
    }
    __syncthreads();   // F
  }
}

// ---------------- fallback: atomic edge kernel (small ws) ----------------

__global__ __launch_bounds__(256, 2) void edge_atomic_kernel(
    const float* __restrict__ x, const int* __restrict__ ei,
    const float* __restrict__ w1, const float* __restrict__ b1,
    const float* __restrict__ w2, const float* __restrict__ b2,
    unsigned int* aggu, const int* __restrict__ flag64, int N, int E) {
  __shared__ unsigned short uA[EB * PADROW];
  __shared__ float w1s[6 * NHID];
  __shared__ float b1s[NHID], b2s[NHID];
  __shared__ int es[EB], ed[EB];

  const int t = threadIdx.x;
  const int lane = t & 63;
  const int w = t >> 6;
  const int m = lane & 15;
  const int q = lane >> 4;

  for (int i = t; i < 6 * NHID; i += 256) w1s[i] = w1[i];
  if (t < NHID) { b1s[t] = b1[t]; b2s[t] = b2[t]; }

  short8 bf[32];
  load_bfrags(w2, bf, m, q);

  const bool is64 = (flag64[0] != 0);
  const int nb = (E + EB - 1) / EB;

  for (int batch = blockIdx.x; batch < nb; batch += gridDim.x) {
    const int gbase = batch * EB;
    if (t < EB) {
      int e = gbase + t;
      es[t] = (e < E) ? (is64 ? ei[2 * e] : ei[e]) : 0;
    } else if (t < 2 * EB) {
      int tt = t - EB;
      int e = gbase + tt;
      ed[tt] = (e < E) ? (is64 ? ei[2 * E + 2 * e] : ei[E + e]) : 0;
    }
    __syncthreads();
    {
      const int e = t >> 2;
      const int c0 = (t & 3) * 32;
      const int si = es[e], di = ed[e];
      float xi0 = x[di * 3], xi1 = x[di * 3 + 1], xi2 = x[di * 3 + 2];
      float msg[6];
      msg[0] = xi0; msg[1] = xi1; msg[2] = xi2;
      msg[3] = x[si * 3] - xi0; msg[4] = x[si * 3 + 1] - xi1; msg[5] = x[si * 3 + 2] - xi2;
      unsigned int* d32 = (unsigned int*)uA;
      const int base32 = (e * PADROW + c0) >> 1;
      #pragma unroll
      for (int cc = 0; cc < 32; cc += 2) {
        float u0 = b1s[c0 + cc], u1 = b1s[c0 + cc + 1];
        #pragma unroll
        for (int d = 0; d < 6; ++d) {
          u0 += msg[d] * w1s[d * NHID + c0 + cc];
          u1 += msg[d] * w1s[d * NHID + c0 + cc + 1];
        }
        d32[base32 + (cc >> 1)] = pack2(fmaxf(u0, 0.f), fmaxf(u1, 0.f));
      }
    }
    __syncthreads();

    floatx4 acc[8];
    #pragma unroll
    for (int nt = 0; nt < 8; ++nt) { floatx4 z = {0.f, 0.f, 0.f, 0.f}; acc[nt] = z; }
    mfma_block(uA, bf, acc, w, m, q);

    #pragma unroll
    for (int nt = 0; nt < 8; ++nt) {
      const int c = nt * 16 + m;
      const float bb = b2s[c];
      const int kst = m * 8 + nt;
      #pragma unroll
      for (int r = 0; r < 4; ++r) {
        const int erow = 16 * w + q * 4 + r;
        if (gbase + erow < E) {
          float hb = acc[nt][r] + bb;
          if (hb > 0.f) {
            unsigned int v = (unsigned int)f2bf(hb);
            casmax(aggu + (size_t)ed[erow] * 64 + (kst >> 1), v << (16 * (kst & 1)));
          }
        }
      }
    }
    __syncthreads();
  }
}

// ---------------- fused node MLPs: enc (w3) + dec (w4,w5), agg16 input ----------------
// R9 structure (barriers B0/B1/B2/B3) — R10's barrier removal regressed.

__global__ __launch_bounds__(256, 2) void encdec_kernel(
    const float* __restrict__ w3, const float* __restrict__ b3,
    const float* __restrict__ w4, const float* __restrict__ b4,
    const float* __restrict__ w5, const float* __restrict__ b5,
    const float* __restrict__ pos, const unsigned short* __restrict__ agg16,
    float* __restrict__ out, int N) {
  __shared__ unsigned short uA[EB * PADROW];
  __shared__ short8 w4f[2048];                    // k-permuted w4 frags
  __shared__ float w5s[NHID * 3];

  const int t = threadIdx.x;
  const int lane = t & 63;
  const int w = t >> 6;
  const int m = lane & 15;
  const int q = lane >> 4;

  float b3c[8], b4c[8];
  #pragma unroll
  for (int nt = 0; nt < 8; ++nt) { b3c[nt] = b3[nt * 16 + m]; b4c[nt] = b4[nt * 16 + m]; }

  short8 bf3[32];
  load_bfrags_perm(w3, bf3, m, q);                // k-permuted (agg16 is kstore-ordered)

  for (int idx = t; idx < 2048; idx += 256) {
    const int fg = idx >> 6, ln = idx & 63;
    const int mm = ln & 15;
    const int kc = fg >> 3, nt = fg & 7;
    short8 v;
    #pragma unroll
    for (int j = 0; j < 8; ++j) {
      const int khw = kc * 32 + (ln >> 4) * 8 + j;
      const int ctrue = ((khw & 7) << 4) | (khw >> 3);
      v[j] = (short)f2bf(w4[ctrue * NHID + nt * 16 + mm]);
    }
    w4f[idx] = v;
  }
  for (int i = t; i < NHID * 3; i += 256) w5s[i] = w5[i];
  const float b50 = b5[0], b51 = b5[1], b52 = b5[2];

  const int ch = t & 15;
  const int rr = t >> 4;
  const int nb = (N + EB - 1) / EB;
  __syncthreads();

  uint4 rv[4];
  const uint4 uz = make_uint4(0u, 0u, 0u, 0u);
  {
    const int b0 = blockIdx.x;
    #pragma unroll
    for (int k = 0; k < 4; ++k) {
      const int node = b0 * EB + rr + 16 * k;
      rv[k] = (b0 < nb && node < N) ? ((const uint4*)agg16)[(size_t)node * 16 + ch] : uz;
    }
  }

  for (int batch = blockIdx.x; batch < nb; batch += gridDim.x) {
    const int base = batch * EB;
    #pragma unroll
    for (int k = 0; k < 4; ++k)
      *(uint4*)(&uA[(rr + 16 * k) * PADROW + ch * 8]) = rv[k];
    __syncthreads();   // B0

    {
      const int nxb = batch + gridDim.x;
      #pragma unroll
      for (int k = 0; k < 4; ++k) {
        const int node = nxb * EB + rr + 16 * k;
        rv[k] = (nxb < nb && node < N) ? ((const uint4*)agg16)[(size_t)node * 16 + ch] : uz;
      }
    }

    floatx4 acc[8];
    #pragma unroll
    for (int nt = 0; nt < 8; ++nt) { floatx4 z = {0.f, 0.f, 0.f, 0.f}; acc[nt] = z; }
    mfma_block(uA, bf3, acc, w, m, q);
    __syncthreads();   // B1

    #pragma unroll
    for (int r = 0; r < 4; ++r) {
      union { short8 s; uint4 u; } cv;
      cv.u = make_uint4(
        pkbf(acc[0][r] + b3c[0], acc[1][r] + b3c[1]),
        pkbf(acc[2][r] + b3c[2], acc[3][r] + b3c[3]),
        pkbf(acc[4][r] + b3c[4], acc[5][r] + b3c[5]),
        pkbf(acc[6][r] + b3c[6], acc[7][r] + b3c[7]));
      *(short8*)(&uA[(16 * w + q * 4 + r) * PADROW + m * 8]) = cv.s;
    }
    __syncthreads();   // B2

    #pragma unroll
    for (int nt = 0; nt < 8; ++nt) { floatx4 z = {0.f, 0.f, 0.f, 0.f}; acc[nt] = z; }
    #pragma unroll
    for (int kc = 0; kc < 4; ++kc) {
      short8 a = *(const short8*)(&uA[(16 * w + m) * PADROW + kc * 32 + q * 8]);
      #pragma unroll
      for (int nt = 0; nt < 8; ++nt)
        acc[nt] = __builtin_amdgcn_mfma_f32_16x16x32_bf16(a, w4f[(kc * 8 + nt) * 64 + lane],
                                                          acc[nt], 0, 0, 0);
    }

    float p[4][3];
    #pragma unroll
    for (int r = 0; r < 4; ++r) { p[r][0] = 0.f; p[r][1] = 0.f; p[r][2] = 0.f; }
    #pragma unroll
    for (int nt = 0; nt < 8; ++nt) {
      const int c = nt * 16 + m;
      const float bb = b4c[nt];
      const float w50 = w5s[c * 3], w51 = w5s[c * 3 + 1], w52 = w5s[c * 3 + 2];
      #pragma unroll
      for (int r = 0; r < 4; ++r) {
        float tv = fmaxf(acc[nt][r] + bb, 0.f);
        p[r][0] += tv * w50; p[r][1] += tv * w51; p[r][2] += tv * w52;
      }
    }
    #pragma unroll
    for (int off = 8; off >= 1; off >>= 1) {
      #pragma unroll
      for (int r = 0; r < 4; ++r) {
        p[r][0] += __shfl_xor(p[r][0], off, 16);
        p[r][1] += __shfl_xor(p[r][1], off, 16);
        p[r][2] += __shfl_xor(p[r][2], off, 16);
      }
    }
    if (m == 0) {
      #pragma unroll
      for (int r = 0; r < 4; ++r) {
        const int node = base + 16 * w + q * 4 + r;
        if (node < N) {
          out[node * 3]     = pos[node * 3]     + 0.1f * tanhf(p[r][0] + b50);
          out[node * 3 + 1] = pos[node * 3 + 1] + 0.1f * tanhf(p[r][1] + b51);
          out[node * 3 + 2] = pos[node * 3 + 2] + 0.1f * tanhf(p[r][2] + b52);
        }
      }
    }
    __syncthreads();   // B3
  }
}

extern "C" void kernel_launch(void* const* d_in, const int* in_sizes, int n_in,
                              void* d_out, int out_size, void* d_ws, size_t ws_size,
                              hipStream_t stream) {
  const float* x   = (const float*)d_in[0];
  const float* pos = (const float*)d_in[1];
  const int*   ei  = (const int*)d_in[2];
  const float* w1  = (const float*)d_in[3];
  const float* b1  = (const float*)d_in[4];
  const float* w2  = (const float*)d_in[5];
  const float* b2  = (const float*)d_in[6];
  const float* w3  = (const float*)d_in[7];
  const float* b3  = (const float*)d_in[8];
  const float* w4  = (const float*)d_in[9];
  const float* b4  = (const float*)d_in[10];
  const float* w5  = (const float*)d_in[11];
  const float* b5  = (const float*)d_in[12];
  float* out = (float*)d_out;

  const int N = in_sizes[0] / 3;
  const int E = in_sizes[2] / 2;
  const int nbuck = (N + 255) >> 8;

  char* ws = (char*)d_ws;
  unsigned short* agg16 = (unsigned short*)ws;                // N*128 u16 (kstore order)
  const size_t aggB = (size_t)N * NHID * sizeof(unsigned short);
  int2* mid    = (int2*)(ws + aggB);
  int2* sorted = (int2*)(ws + aggB + (size_t)E * 8);
  int*  mat    = (int*)(ws + aggB + (size_t)E * 16);
  int*  btot   = mat + (size_t)nbuck * PB;
  int*  bstart = btot + nbuck;
  const size_t needed = aggB + (size_t)E * 16 + ((size_t)nbuck * PB + nbuck + 520) * 4;

  if (ws_size >= needed && nbuck <= 511 && E >= 64) {
    part_hist<<<2048, 256, 0, stream>>>(ei, mat, E, nbuck, (float4*)agg16, N * 16);
    scan_rows<<<nbuck, 256, 0, stream>>>(mat, btot, nbuck);
    part_scatter<<<PB, 512, 0, stream>>>(ei, mat, btot, bstart, mid, E, nbuck);
    bucket_sort<<<nbuck, 512, 0, stream>>>(mid, bstart, sorted);
    edge_sorted_kernel<<<512, 512, 0, stream>>>(x, sorted, w1, b1, w2, b2,
                                                (unsigned int*)agg16, N, E);
  } else {
    int* flag2 = (int*)(ws + aggB);
    zero_detect_kernel<<<2048, 256, 0, stream>>>((float4*)agg16, N * 16, ei, flag2);
    edge_atomic_kernel<<<512, 256, 0, stream>>>(x, ei, w1, b1, w2, b2,
                                                (unsigned int*)agg16, flag2, N, E);
  }
  encdec_kernel<<<512, 256, 0, stream>>>(w3, b3, w4, b4, w5, b5, pos, agg16, out, N);
}